// Round 1
// baseline (121.280 us; speedup 1.0000x reference)
//
#include <hip/hip_runtime.h>

// Cost volume loss: pred/target (8,3,512,512) f32.
// Per pixel: min over 5x5 offsets (zero-padded target) of mean_C |pred - target_patch|,
// then global mean. Output: single f32 scalar.

#define H_DIM 512
#define W_DIM 512
#define N_DIM 8
#define C_DIM 3
#define HW (H_DIM * W_DIM)
#define NPIX (N_DIM * HW)

__global__ __launch_bounds__(256) void cvl_main(const float* __restrict__ pred,
                                                const float* __restrict__ targ,
                                                double* __restrict__ acc) {
    const int idx = blockIdx.x * 256 + threadIdx.x;   // grid exactly covers NPIX
    const int w = idx & (W_DIM - 1);
    const int h = (idx >> 9) & (H_DIM - 1);
    const int n = idx >> 18;

    const float* p = pred + (size_t)n * C_DIM * HW + h * W_DIM + w;
    const float p0 = p[0];
    const float p1 = p[HW];
    const float p2 = p[2 * HW];

    const float* t = targ + (size_t)n * C_DIM * HW;

    // Channel-sum at an out-of-bounds (zero-padded) location:
    const float s_oob = fabsf(p0) + fabsf(p1) + fabsf(p2);

    float best = 1e30f;
#pragma unroll
    for (int di = -2; di <= 2; ++di) {
        const int hh = h + di;
        const bool hin = (unsigned)hh < (unsigned)H_DIM;
#pragma unroll
        for (int dj = -2; dj <= 2; ++dj) {
            const int ww = w + dj;
            float s;
            if (hin && (unsigned)ww < (unsigned)W_DIM) {
                const float* tp = t + hh * W_DIM + ww;
                s = fabsf(p0 - tp[0]) + fabsf(p1 - tp[HW]) + fabsf(p2 - tp[2 * HW]);
            } else {
                s = s_oob;
            }
            best = fminf(best, s);
        }
    }

    // Block reduction: wave shuffle then LDS.
    float v = best;
#pragma unroll
    for (int o = 32; o > 0; o >>= 1) v += __shfl_down(v, o, 64);

    __shared__ float ws[4];
    const int lane = threadIdx.x & 63;
    const int wid = threadIdx.x >> 6;
    if (lane == 0) ws[wid] = v;
    __syncthreads();
    if (threadIdx.x == 0) {
        const float bs = ws[0] + ws[1] + ws[2] + ws[3];
        atomicAdd(acc, (double)bs);
    }
}

__global__ void cvl_final(const double* __restrict__ acc, float* __restrict__ out) {
    out[0] = (float)(acc[0] / (3.0 * (double)NPIX));
}

extern "C" void kernel_launch(void* const* d_in, const int* in_sizes, int n_in,
                              void* d_out, int out_size, void* d_ws, size_t ws_size,
                              hipStream_t stream) {
    const float* pred = (const float*)d_in[0];
    const float* targ = (const float*)d_in[1];
    float* out = (float*)d_out;
    double* acc = (double*)d_ws;

    hipMemsetAsync(acc, 0, sizeof(double), stream);

    const int nblocks = NPIX / 256;  // 8192
    cvl_main<<<nblocks, 256, 0, stream>>>(pred, targ, acc);
    cvl_final<<<1, 1, 0, stream>>>(acc, out);
}

// Round 2
// 34.244 us; speedup vs baseline: 3.5416x; 3.5416x over previous
//
#include <hip/hip_runtime.h>

// Cost volume loss: pred/target (8,3,512,512) f32.
// Per pixel: min over 5x5 offsets (zero-padded target) of mean_C |pred - patch|,
// then global mean. Output: single f32 scalar.
//
// Layout: thread = 4 wide (float4) x 2 tall. Block 256 threads = 128 cols x 2
// row-groups -> covers 4 rows x 512 cols. Grid = 8 n * 128 hgrps = 1024 blocks.

#define H_DIM 512
#define W_DIM 512
#define N_DIM 8
#define C_DIM 3
#define HW (H_DIM * W_DIM)
#define CHW (C_DIM * HW)
#define NPIX (N_DIM * HW)

__global__ __launch_bounds__(256) void cvl_main(const float* __restrict__ pred,
                                                const float* __restrict__ targ,
                                                double* __restrict__ acc) {
    const int tid = threadIdx.x;
    const int col = tid & 127;        // 0..127
    const int rg  = tid >> 7;         // 0..1
    const int bid = blockIdx.x;       // 0..1023
    const int n   = bid >> 7;         // 0..7
    const int hg  = bid & 127;        // 0..127
    const int h0  = hg * 4 + rg * 2;  // first of this thread's 2 rows
    const int w0  = col * 4;          // first of this thread's 4 cols

    const size_t nbase = (size_t)n * CHW;

    // ---- pred: 2 rows x 3 channels x 4 pixels, in registers ----
    float pf[2][3][4];
#pragma unroll
    for (int r = 0; r < 2; ++r) {
#pragma unroll
        for (int c = 0; c < 3; ++c) {
            const float4 v = *(const float4*)(pred + nbase + (size_t)c * HW +
                                              (size_t)(h0 + r) * W_DIM + w0);
            pf[r][c][0] = v.x; pf[r][c][1] = v.y; pf[r][c][2] = v.z; pf[r][c][3] = v.w;
        }
    }

    // Channel-sum |pred| (value of s at any zero-padded offset)
    float soob[2][4];
#pragma unroll
    for (int r = 0; r < 2; ++r)
#pragma unroll
        for (int px = 0; px < 4; ++px)
            soob[r][px] = fabsf(pf[r][0][px]) + fabsf(pf[r][1][px]) + fabsf(pf[r][2][px]);

    float best[2][4];
#pragma unroll
    for (int r = 0; r < 2; ++r)
#pragma unroll
        for (int px = 0; px < 4; ++px)
            best[r][px] = 3.0e38f;

    const bool wlo = (w0 == 0);            // left-edge lane
    const bool whi = (w0 == W_DIM - 4);    // right-edge lane
    const int offm = (w0 - 4 < 0) ? 0 : (w0 - 4);
    const int offp = (w0 + 4 > W_DIM - 4) ? (W_DIM - 4) : (w0 + 4);

    // ---- iterate the 6 target rows this thread's 2 output rows need ----
#pragma unroll
    for (int r = 0; r < 6; ++r) {
        const int hh = h0 - 2 + r;
        if (hh >= 0 && hh < H_DIM) {  // wave-uniform (h0 uniform per wave)
            // 12-float window per channel: w0-4 .. w0+7 (clamped at edges)
            float tw[3][12];
#pragma unroll
            for (int c = 0; c < 3; ++c) {
                const float* rowp = targ + nbase + (size_t)c * HW + (size_t)hh * W_DIM;
                const float4 a = *(const float4*)(rowp + offm);
                const float4 b = *(const float4*)(rowp + w0);
                const float4 d = *(const float4*)(rowp + offp);
                tw[c][0] = a.x;  tw[c][1] = a.y;  tw[c][2]  = a.z;  tw[c][3]  = a.w;
                tw[c][4] = b.x;  tw[c][5] = b.y;  tw[c][6]  = b.z;  tw[c][7]  = b.w;
                tw[c][8] = d.x;  tw[c][9] = d.y;  tw[c][10] = d.z;  tw[c][11] = d.w;
            }
#pragma unroll
            for (int orow = 0; orow < 2; ++orow) {
                const int di = r - 2 - orow;          // compile-time after unroll
                if (di >= -2 && di <= 2) {
#pragma unroll
                    for (int px = 0; px < 4; ++px) {
#pragma unroll
                        for (int dj = -2; dj <= 2; ++dj) {
                            const int ix = 4 + px + dj;  // 2..9
                            float s = fabsf(pf[orow][0][px] - tw[0][ix])
                                    + fabsf(pf[orow][1][px] - tw[1][ix])
                                    + fabsf(pf[orow][2][px] - tw[2][ix]);
                            if (px + dj < 0)      s = wlo ? soob[orow][px] : s;
                            else if (px + dj > 3) s = whi ? soob[orow][px] : s;
                            best[orow][px] = fminf(best[orow][px], s);
                        }
                    }
                }
            }
        } else {
            // whole target row is zero-pad: every dj contributes soob
#pragma unroll
            for (int orow = 0; orow < 2; ++orow) {
                const int di = r - 2 - orow;
                if (di >= -2 && di <= 2) {
#pragma unroll
                    for (int px = 0; px < 4; ++px)
                        best[orow][px] = fminf(best[orow][px], soob[orow][px]);
                }
            }
        }
    }

    // ---- reduce: 8 pixels -> thread, wave shuffle, LDS, one atomic/block ----
    float v = 0.0f;
#pragma unroll
    for (int r = 0; r < 2; ++r)
#pragma unroll
        for (int px = 0; px < 4; ++px)
            v += best[r][px];

#pragma unroll
    for (int o = 32; o > 0; o >>= 1) v += __shfl_down(v, o, 64);

    __shared__ float ws[4];
    const int lane = tid & 63;
    const int wid  = tid >> 6;
    if (lane == 0) ws[wid] = v;
    __syncthreads();
    if (tid == 0) {
        const float bs = ws[0] + ws[1] + ws[2] + ws[3];
        atomicAdd(acc, (double)bs);
    }
}

__global__ void cvl_final(const double* __restrict__ acc, float* __restrict__ out) {
    out[0] = (float)(acc[0] / (3.0 * (double)NPIX));
}

extern "C" void kernel_launch(void* const* d_in, const int* in_sizes, int n_in,
                              void* d_out, int out_size, void* d_ws, size_t ws_size,
                              hipStream_t stream) {
    const float* pred = (const float*)d_in[0];
    const float* targ = (const float*)d_in[1];
    float* out = (float*)d_out;
    double* acc = (double*)d_ws;

    hipMemsetAsync(acc, 0, sizeof(double), stream);

    const int nblocks = (N_DIM * H_DIM) / 4;  // 1024 blocks (4 rows per block)
    cvl_main<<<nblocks, 256, 0, stream>>>(pred, targ, acc);
    cvl_final<<<1, 1, 0, stream>>>(acc, out);
}

// Round 3
// 22.401 us; speedup vs baseline: 5.4141x; 1.5287x over previous
//
#include <hip/hip_runtime.h>

// Cost volume loss: pred/target (8,3,512,512) f32.
// Per pixel: min over 5x5 offsets (zero-padded target) of mean_C |pred - patch|,
// then global mean. Output: single f32 scalar.
//
// Thread = 4 cols (float4) x 4 rows. Block 256 threads = 128 cols x 2 row-groups
// -> covers 8 rows x 512 cols. Grid = 8 n * 64 hgrps = 512 blocks.
// Each block writes one float partial to d_ws; final kernel reduces 512 floats.

#define H_DIM 512
#define W_DIM 512
#define N_DIM 8
#define C_DIM 3
#define HW (H_DIM * W_DIM)
#define CHW (C_DIM * HW)
#define NPIX (N_DIM * HW)
#define NBLOCKS 512

__global__ __launch_bounds__(256) void cvl_main(const float* __restrict__ pred,
                                                const float* __restrict__ targ,
                                                float* __restrict__ partial) {
    const int tid = threadIdx.x;
    const int col = tid & 127;        // 0..127
    const int rg  = tid >> 7;         // 0..1
    const int bid = blockIdx.x;       // 0..511
    const int n   = bid >> 6;         // 0..7
    const int hg  = bid & 63;         // 0..63
    const int h0  = hg * 8 + rg * 4;  // first of this thread's 4 rows
    const int w0  = col * 4;          // first of this thread's 4 cols

    const size_t nbase = (size_t)n * CHW;

    // ---- pred: 4 rows x 3 channels x 4 pixels, in registers ----
    float pf[4][3][4];
#pragma unroll
    for (int r = 0; r < 4; ++r) {
#pragma unroll
        for (int c = 0; c < 3; ++c) {
            const float4 v = *(const float4*)(pred + nbase + (size_t)c * HW +
                                              (size_t)(h0 + r) * W_DIM + w0);
            pf[r][c][0] = v.x; pf[r][c][1] = v.y; pf[r][c][2] = v.z; pf[r][c][3] = v.w;
        }
    }

    // Channel-sum |pred| (value of s at any zero-padded offset)
    float soob[4][4];
#pragma unroll
    for (int r = 0; r < 4; ++r)
#pragma unroll
        for (int px = 0; px < 4; ++px)
            soob[r][px] = fabsf(pf[r][0][px]) + fabsf(pf[r][1][px]) + fabsf(pf[r][2][px]);

    float best[4][4];
#pragma unroll
    for (int r = 0; r < 4; ++r)
#pragma unroll
        for (int px = 0; px < 4; ++px)
            best[r][px] = 3.0e38f;

    const bool wlo = (w0 == 0);            // left-edge lane
    const bool whi = (w0 == W_DIM - 4);    // right-edge lane
    const int offm = (w0 - 4 < 0) ? 0 : (w0 - 4);
    const int offp = (w0 + 4 > W_DIM - 4) ? (W_DIM - 4) : (w0 + 4);

    // ---- iterate the 8 target rows this thread's 4 output rows need ----
#pragma unroll
    for (int r = 0; r < 8; ++r) {
        const int hh = h0 - 2 + r;
        if (hh >= 0 && hh < H_DIM) {  // wave-uniform (h0 uniform per wave)
            // 12-float window per channel: w0-4 .. w0+7 (clamped at edges)
            float tw[3][12];
#pragma unroll
            for (int c = 0; c < 3; ++c) {
                const float* rowp = targ + nbase + (size_t)c * HW + (size_t)hh * W_DIM;
                const float4 a = *(const float4*)(rowp + offm);
                const float4 b = *(const float4*)(rowp + w0);
                const float4 d = *(const float4*)(rowp + offp);
                tw[c][0] = a.x;  tw[c][1] = a.y;  tw[c][2]  = a.z;  tw[c][3]  = a.w;
                tw[c][4] = b.x;  tw[c][5] = b.y;  tw[c][6]  = b.z;  tw[c][7]  = b.w;
                tw[c][8] = d.x;  tw[c][9] = d.y;  tw[c][10] = d.z;  tw[c][11] = d.w;
            }
#pragma unroll
            for (int orow = 0; orow < 4; ++orow) {
                const int di = r - 2 - orow;          // compile-time after unroll
                if (di >= -2 && di <= 2) {
#pragma unroll
                    for (int px = 0; px < 4; ++px) {
#pragma unroll
                        for (int dj = -2; dj <= 2; ++dj) {
                            const int ix = 4 + px + dj;  // 2..9
                            float s = fabsf(pf[orow][0][px] - tw[0][ix])
                                    + fabsf(pf[orow][1][px] - tw[1][ix])
                                    + fabsf(pf[orow][2][px] - tw[2][ix]);
                            if (px + dj < 0)      s = wlo ? soob[orow][px] : s;
                            else if (px + dj > 3) s = whi ? soob[orow][px] : s;
                            best[orow][px] = fminf(best[orow][px], s);
                        }
                    }
                }
            }
        } else {
            // whole target row is zero-pad: every dj contributes soob
#pragma unroll
            for (int orow = 0; orow < 4; ++orow) {
                const int di = r - 2 - orow;
                if (di >= -2 && di <= 2) {
#pragma unroll
                    for (int px = 0; px < 4; ++px)
                        best[orow][px] = fminf(best[orow][px], soob[orow][px]);
                }
            }
        }
    }

    // ---- reduce: 16 pixels -> thread, wave shuffle, LDS, one store/block ----
    float v = 0.0f;
#pragma unroll
    for (int r = 0; r < 4; ++r)
#pragma unroll
        for (int px = 0; px < 4; ++px)
            v += best[r][px];

#pragma unroll
    for (int o = 32; o > 0; o >>= 1) v += __shfl_down(v, o, 64);

    __shared__ float ws[4];
    const int lane = tid & 63;
    const int wid  = tid >> 6;
    if (lane == 0) ws[wid] = v;
    __syncthreads();
    if (tid == 0) {
        partial[bid] = ws[0] + ws[1] + ws[2] + ws[3];
    }
}

__global__ __launch_bounds__(256) void cvl_final(const float* __restrict__ partial,
                                                 float* __restrict__ out) {
    const int tid = threadIdx.x;
    double v = (double)partial[tid] + (double)partial[tid + 256];
#pragma unroll
    for (int o = 32; o > 0; o >>= 1) v += __shfl_down(v, o, 64);

    __shared__ double ws[4];
    const int lane = tid & 63;
    const int wid  = tid >> 6;
    if (lane == 0) ws[wid] = v;
    __syncthreads();
    if (tid == 0) {
        const double s = ws[0] + ws[1] + ws[2] + ws[3];
        out[0] = (float)(s / (3.0 * (double)NPIX));
    }
}

extern "C" void kernel_launch(void* const* d_in, const int* in_sizes, int n_in,
                              void* d_out, int out_size, void* d_ws, size_t ws_size,
                              hipStream_t stream) {
    const float* pred = (const float*)d_in[0];
    const float* targ = (const float*)d_in[1];
    float* out = (float*)d_out;
    float* partial = (float*)d_ws;

    cvl_main<<<NBLOCKS, 256, 0, stream>>>(pred, targ, partial);
    cvl_final<<<1, 256, 0, stream>>>(partial, out);
}